// Round 6
// baseline (363.892 us; speedup 1.0000x reference)
//
#include <hip/hip_runtime.h>
#include <hip/hip_bf16.h>
#include <cstdint>
#include <cstddef>

// B=4, S=2048, D=1024, H=16, DK=64. Device I/O dtype: FLOAT32.
// Internal compute: bf16 MFMA with f32 accumulation.
static constexpr int kB = 4, kS = 2048, kD = 1024, kH = 16, kDK = 64;
static constexpr int kM = kB * kS;

typedef __attribute__((ext_vector_type(8))) __bf16 bf16x8;
typedef __attribute__((ext_vector_type(4))) __bf16 bf16x4;
typedef __attribute__((ext_vector_type(4))) float f32x4;

#define MFMA_BF16(a, b, c) __builtin_amdgcn_mfma_f32_16x16x32_bf16((a), (b), (c), 0, 0, 0)

#define GLDS16(gp, lp)                                                        \
  __builtin_amdgcn_global_load_lds(                                           \
      (__attribute__((address_space(1))) void*)(gp),                          \
      (__attribute__((address_space(3))) void*)(lp), 16, 0, 0)

// ---------------------------------------------------------------------------
// f32 -> bf16 converters
// ---------------------------------------------------------------------------
__device__ __forceinline__ bf16x8 cvt8(const float* s, int i) {
  const float4 a = ((const float4*)s)[i * 2 + 0];
  const float4 b = ((const float4*)s)[i * 2 + 1];
  bf16x8 o;
  o[0] = (__bf16)a.x; o[1] = (__bf16)a.y; o[2] = (__bf16)a.z; o[3] = (__bf16)a.w;
  o[4] = (__bf16)b.x; o[5] = (__bf16)b.y; o[6] = (__bf16)b.z; o[7] = (__bf16)b.w;
  return o;
}

__global__ __launch_bounds__(256) void cvt_f32_bf16(
    const float* __restrict__ src, __bf16* __restrict__ dst, int n8) {
  const int i = blockIdx.x * 256 + threadIdx.x;
  if (i >= n8) return;
  ((bf16x8*)dst)[i] = cvt8(src, i);
}

// all 7 tensors (3 activations @4096 blocks + 4 weights @512) in ONE launch
__global__ __launch_bounds__(256) void cvt_all(
    const float* __restrict__ q, const float* __restrict__ k,
    const float* __restrict__ v, const float* __restrict__ wq,
    const float* __restrict__ wk, const float* __restrict__ wv,
    const float* __restrict__ wo, __bf16* __restrict__ dq,
    __bf16* __restrict__ dk, __bf16* __restrict__ dv,
    __bf16* __restrict__ dwq, __bf16* __restrict__ dwk,
    __bf16* __restrict__ dwv, __bf16* __restrict__ dwo) {
  int bid = blockIdx.x;
  const float* s;
  __bf16* d;
  int i;
  if (bid < 3 * 4096) {
    const int seg = bid >> 12;
    i = (bid & 4095) * 256 + threadIdx.x;
    s = seg == 0 ? q : seg == 1 ? k : v;
    d = seg == 0 ? dq : seg == 1 ? dk : dv;
  } else {
    bid -= 3 * 4096;
    const int seg = bid >> 9;
    i = (bid & 511) * 256 + threadIdx.x;
    s = seg == 0 ? wq : seg == 1 ? wk : seg == 2 ? wv : wo;
    d = seg == 0 ? dwq : seg == 1 ? dwk : seg == 2 ? dwv : dwo;
  }
  ((bf16x8*)d)[i] = cvt8(s, i);
}

// ---------------------------------------------------------------------------
// GEMM core: C[M,N] = A[M,K]*W[N,K]^T + bias; N=K=1024. MT = M-tile (128/64).
// BK=64, XOR-granule LDS swizzle (round-4 verified, 0 bank conflicts).
// mode 0: out[m*1024+n] ; mode 1: [b][h][s][dk] ; mode 2: [b][h][dk][s]
// ---------------------------------------------------------------------------
template <int MT, typename OutT>
__device__ __forceinline__ void gemm_core(
    const __bf16* __restrict__ A, const __bf16* __restrict__ W,
    const float* __restrict__ bias, OutT* __restrict__ out, int mode, int bid,
    __bf16* As, __bf16* Ws) {
  constexpr int RT = MT / 32;     // A-frag tiles per wave
  constexpr int AISS = MT / 32;   // staging issues for A
  constexpr int MTILES = 8192 / MT;
  const int tid = threadIdx.x;
  const int wave = tid >> 6, lane = tid & 63;
  const int col = lane & 15, quad = lane >> 4;
  const int m0 = (bid % MTILES) * MT;
  const int n0 = (bid / MTILES) * 128;
  const int wr = (wave & 1) * (MT / 2);
  const int wc = (wave >> 1) * 64;

  f32x4 acc[RT][4] = {};

  const int g0f = ((quad) ^ (col & 7)) * 16;       // frag-read byte offsets
  const int g1f = ((quad + 4) ^ (col & 7)) * 16;

  for (int k0 = 0; k0 < 1024; k0 += 64) {
#pragma unroll
    for (int i = 0; i < AISS; ++i) {
      const int s = i * 256 + tid;
      GLDS16(A + (size_t)(m0 + (s >> 3)) * 1024 + k0 +
                 (((s & 7) ^ ((s >> 3) & 7)) * 8),
             (char*)As + i * 4096 + wave * 1024);
    }
#pragma unroll
    for (int i = 0; i < 4; ++i) {
      const int s = i * 256 + tid;
      GLDS16(W + (size_t)(n0 + (s >> 3)) * 1024 + k0 +
                 (((s & 7) ^ ((s >> 3) & 7)) * 8),
             (char*)Ws + i * 4096 + wave * 1024);
    }
    __syncthreads();
#pragma unroll
    for (int h = 0; h < 2; ++h) {
      const int go = h ? g1f : g0f;
      bf16x8 af[RT], wf[4];
#pragma unroll
      for (int t = 0; t < RT; ++t)
        af[t] = *(const bf16x8*)((const char*)As + (wr + t * 16 + col) * 128 + go);
#pragma unroll
      for (int t = 0; t < 4; ++t)
        wf[t] = *(const bf16x8*)((const char*)Ws + (wc + t * 16 + col) * 128 + go);
#pragma unroll
      for (int rt = 0; rt < RT; ++rt)
#pragma unroll
        for (int ct = 0; ct < 4; ++ct)
          acc[rt][ct] = MFMA_BF16(af[rt], wf[ct], acc[rt][ct]);
    }
    __syncthreads();
  }

  // epilogue: C/D row = quad*4+r, col = lane&15
#pragma unroll
  for (int ct = 0; ct < 4; ++ct) {
    const int n = n0 + wc + ct * 16 + col;
    const float bb = bias[n];
#pragma unroll
    for (int rt = 0; rt < RT; ++rt) {
#pragma unroll
      for (int r = 0; r < 4; ++r) {
        const int m = m0 + wr + rt * 16 + quad * 4 + r;
        const float v = acc[rt][ct][r] + bb;
        size_t idx;
        if (mode == 0) {
          idx = (size_t)m * 1024 + n;
        } else {
          const int b = m >> 11, s = m & 2047;
          const int h2 = n >> 6, dk = n & 63;
          if (mode == 1)
            idx = ((size_t)(b * 16 + h2) * 2048 + s) * 64 + dk;
          else
            idx = ((size_t)(b * 16 + h2) * 64 + dk) * 2048 + s;
        }
        out[idx] = (OutT)v;
      }
    }
  }
}

template <int MODE, int MT, typename OutT>
__global__ __launch_bounds__(256) void gemm_one(
    const __bf16* __restrict__ A, const __bf16* __restrict__ W,
    const float* __restrict__ bias, OutT* __restrict__ out) {
  __shared__ __align__(16) __bf16 As[MT * 64];
  __shared__ __align__(16) __bf16 Ws[128 * 64];
  gemm_core<MT, OutT>(A, W, bias, out, MODE, blockIdx.x, As, Ws);
}

// Q/K/V projections fused into one 1536-block launch
__global__ __launch_bounds__(256) void gemm_qkv(
    const __bf16* __restrict__ Aq, const __bf16* __restrict__ Ak,
    const __bf16* __restrict__ Av, const __bf16* __restrict__ Wqb,
    const __bf16* __restrict__ Wkb, const __bf16* __restrict__ Wvb,
    const float* __restrict__ bq, const float* __restrict__ bk,
    const float* __restrict__ bv, __bf16* __restrict__ Qw,
    __bf16* __restrict__ Kw, __bf16* __restrict__ Vw) {
  __shared__ __align__(16) __bf16 As[128 * 64];
  __shared__ __align__(16) __bf16 Ws[128 * 64];
  const int seg = blockIdx.x >> 9;
  const int bid = blockIdx.x & 511;
  const __bf16* A = seg == 0 ? Aq : seg == 1 ? Ak : Av;
  const __bf16* W = seg == 0 ? Wqb : seg == 1 ? Wkb : Wvb;
  const float* bias = seg == 0 ? bq : seg == 1 ? bk : bv;
  __bf16* out = seg == 0 ? Qw : seg == 1 ? Kw : Vw;
  gemm_core<128, __bf16>(A, W, bias, out, seg == 2 ? 2 : 1, bid, As, Ws);
}

// ---------------------------------------------------------------------------
// Causal flash attention v5 (fixed): S^T formulation, zero P-LDS, zero shuffles.
//  - S^T = K·Q^T with bit2<->bit3-permuted K rows in LDS. C-register (quad,r)
//    of tile kt holds key = k0 + 32*(kt>>1) + quad*8 + (kt&1)*4 + r  == the
//    P^T B-operand element j=(kt&1)*4+r of key-half kh=kt>>1. Pack in-lane.
//  - l = per-lane partial sums + 2 shfl_xor at epilogue.
//  - K/V double-buffered LDS, ONE barrier per chunk (full-chunk prefetch).
// ---------------------------------------------------------------------------
__global__ __launch_bounds__(256, 4) void flash_attn(
    const __bf16* __restrict__ Q, const __bf16* __restrict__ K,
    const __bf16* __restrict__ Vt, __bf16* __restrict__ ctx) {
  __shared__ __align__(16) __bf16 Ks[2][64 * 64];  // [key-permuted][dk] swizzled
  __shared__ __align__(16) __bf16 Vs[2][64 * 64];  // [d][key] swizzled

  const int tid = threadIdx.x;
  const int wave = tid >> 6, lane = tid & 63;
  const int col = lane & 15, quad = lane >> 4;
  const int bh = blockIdx.x >> 4;
  const int pair = blockIdx.x & 15;
  const int b = bh >> 4, h = bh & 15;
  const int t_lo = pair, t_hi = 31 - pair;
  const int q0f[2] = {t_lo * 64 + wave * 16, t_hi * 64 + wave * 16};

  constexpr float SCL = 0.18033688011112042f;  // (1/8) * log2(e)

  // Q B-fragments: B[k=dk=quad*8+j][n=q=col]
  bf16x8 qf[2][2];
#pragma unroll
  for (int f = 0; f < 2; ++f) {
    const __bf16* Qp = Q + ((size_t)bh * kS + q0f[f] + col) * 64 + quad * 8;
    qf[f][0] = *(const bf16x8*)Qp;
    qf[f][1] = *(const bf16x8*)(Qp + 32);
  }

  f32x4 o[2][4] = {};       // O^T accum: lane holds O^T[d=dt*16+quad*4+r][q=col]
  float lsum[2] = {0.f, 0.f};

  const __bf16* Kg = K + (size_t)bh * kS * 64;
  const __bf16* Vg = Vt + (size_t)bh * 64 * kS;

  // staging: row = slot>>3; granule XOR swizzle; K rows bit2<->bit3 permuted.
  const int row0 = tid >> 3;
  const int g0 = ((tid & 7) ^ (row0 & 7)) * 8;
  const int ksrc0 = (row0 & ~12) | ((row0 & 4) << 1) | ((row0 & 8) >> 1);

  auto stage = [&](int c, int buf) {
    const int k0 = c * 64;
    char* KB = (char*)Ks[buf] + wave * 1024;
    char* VB = (char*)Vs[buf] + wave * 1024;
    GLDS16(Kg + (size_t)(k0 + ksrc0) * 64 + g0, KB);
    GLDS16(Vg + (size_t)row0 * kS + k0 + g0, VB);
    GLDS16(Kg + (size_t)(k0 + ksrc0 + 32) * 64 + g0, KB + 4096);
    GLDS16(Vg + (size_t)(row0 + 32) * kS + k0 + g0, VB + 4096);
  };

  const int kq0 = ((quad) ^ (col & 7)) * 16;      // frag granule offsets
  const int kq1 = ((quad + 4) ^ (col & 7)) * 16;  // (row&7 == col&7 by design)

  stage(0, 0);

  for (int c = 0; c <= t_hi; ++c) {
    __syncthreads();  // drains prefetch GLDS; publishes buf (c&1)
    if (c < t_hi) stage(c + 1, (c + 1) & 1);
    const bool lo = (c <= t_lo);
    const bool d0 = (c == t_lo), d1 = (c == t_hi);
    const int k0 = c * 64;
    const char* KB = (const char*)Ks[c & 1];
    const char* VB = (const char*)Vs[c & 1];

    bf16x8 pb[2][2];  // [frag][key-half] P^T B-operand, built in-lane
#pragma unroll
    for (int kt = 0; kt < 4; ++kt) {
      // permuted K row: holds key = 32*(kt>>1) + quad*8 + (kt&1)*4 + r at m
      const int krow = (col & 7) | ((kt & 1) << 3) | ((col & 8) << 1) |
                       ((kt >> 1) << 5);
      const bf16x8 kf0 = *(const bf16x8*)(KB + krow * 128 + kq0);
      const bf16x8 kf1 = *(const bf16x8*)(KB + krow * 128 + kq1);
      f32x4 z = {};
      const f32x4 s1 = MFMA_BF16(kf1, qf[1][1], MFMA_BF16(kf0, qf[1][0], z));
      f32x4 s0 = z;
      if (lo) s0 = MFMA_BF16(kf1, qf[0][1], MFMA_BF16(kf0, qf[0][0], z));
      // this lane's key for register r (FIX: include the 32*(kt>>1) term)
      const int kbase = k0 + (kt >> 1) * 32 + quad * 8 + (kt & 1) * 4;
#pragma unroll
      for (int r = 0; r < 4; ++r) {
        float e1 = __builtin_amdgcn_exp2f(s1[r] * SCL);
        if (d1 && (kbase + r > q0f[1] + col)) e1 = 0.0f;
        lsum[1] += e1;
        pb[1][kt >> 1][(kt & 1) * 4 + r] = (__bf16)e1;
        float e0 = __builtin_amdgcn_exp2f(s0[r] * SCL);
        if (d0 && (kbase + r > q0f[0] + col)) e0 = 0.0f;
        if (lo) lsum[0] += e0;
        pb[0][kt >> 1][(kt & 1) * 4 + r] = (__bf16)e0;
      }
    }
    // O^T += V^T · P^T
#pragma unroll
    for (int dt = 0; dt < 4; ++dt) {
      const char* vp = VB + (dt * 16 + col) * 128;
      const bf16x8 vf0 = *(const bf16x8*)(vp + kq0);
      const bf16x8 vf1 = *(const bf16x8*)(vp + kq1);
      o[1][dt] = MFMA_BF16(vf1, pb[1][1], MFMA_BF16(vf0, pb[1][0], o[1][dt]));
      if (lo) o[0][dt] = MFMA_BF16(vf1, pb[0][1], MFMA_BF16(vf0, pb[0][0], o[0][dt]));
    }
  }

  // epilogue: l = sum over quads; write O^T lanes as packed 8B rows of ctx
#pragma unroll
  for (int f = 0; f < 2; ++f) {
    float l = lsum[f];
    l += __shfl_xor(l, 16, 64);
    l += __shfl_xor(l, 32, 64);
    const float inv = 1.0f / l;
    __bf16* cp = ctx + ((size_t)b * kS + q0f[f] + col) * kD + h * 64 + quad * 4;
#pragma unroll
    for (int dt = 0; dt < 4; ++dt) {
      bf16x4 w;
#pragma unroll
      for (int r = 0; r < 4; ++r) w[r] = (__bf16)(o[f][dt][r] * inv);
      *(bf16x4*)(cp + dt * 16) = w;
    }
  }
}

// ---------------------------------------------------------------------------
extern "C" void kernel_launch(void* const* d_in, const int* in_sizes, int n_in,
                              void* d_out, int out_size, void* d_ws, size_t ws_size,
                              hipStream_t stream) {
  const float* query = (const float*)d_in[0];
  const float* key_  = (const float*)d_in[1];
  const float* value = (const float*)d_in[2];
  const float* Wq = (const float*)d_in[4];
  const float* bq = (const float*)d_in[5];
  const float* Wk = (const float*)d_in[6];
  const float* bk = (const float*)d_in[7];
  const float* Wv = (const float*)d_in[8];
  const float* bv = (const float*)d_in[9];
  const float* Wo = (const float*)d_in[10];
  const float* bo = (const float*)d_in[11];

  const size_t e = (size_t)kM * kD;       // 8,388,608
  const size_t w = (size_t)kD * kD;       // 1,048,576
  float* out = (float*)d_out;

  const size_t REQ = (6 * e + 4 * w) * sizeof(__bf16);  // ~109 MB

  if (ws_size >= REQ) {
    __bf16* Qw  = (__bf16*)d_ws;
    __bf16* Kw  = Qw + e;
    __bf16* Vw  = Kw + e;     // [B,H,64,S]
    __bf16* Aq  = Vw + e;     // reused as ctx after gemm_qkv
    __bf16* Ak  = Aq + e;
    __bf16* Av  = Ak + e;
    __bf16* Wqb = Av + e;
    __bf16* Wkb = Wqb + w;
    __bf16* Wvb = Wkb + w;
    __bf16* Wob = Wvb + w;

    cvt_all<<<3 * 4096 + 4 * 512, 256, 0, stream>>>(
        query, key_, value, Wq, Wk, Wv, Wo, Aq, Ak, Av, Wqb, Wkb, Wvb, Wob);
    gemm_qkv<<<1536, 256, 0, stream>>>(Aq, Ak, Av, Wqb, Wkb, Wvb, bq, bk, bv,
                                       Qw, Kw, Vw);
    flash_attn<<<kB * kH * 16, 256, 0, stream>>>(Qw, Kw, Vw, Aq);  // ctx -> Aq
    gemm_one<0, 64, float><<<1024, 256, 0, stream>>>(Aq, Wob, bo, out);
  } else {
    // sequential fallback
    __bf16* Qw = (__bf16*)d_ws;
    __bf16* Kw = Qw + e;
    __bf16* Vw = Kw + e;
    __bf16* Ab = Vw + e;
    __bf16* Wb = Ab + e;

    const int actg = (int)(e / 8 / 256);
    const int wg = (int)(w / 8 / 256);
    cvt_f32_bf16<<<actg, 256, 0, stream>>>(query, Ab, (int)(e / 8));
    cvt_f32_bf16<<<wg, 256, 0, stream>>>(Wq, Wb, (int)(w / 8));
    gemm_one<1, 128, __bf16><<<512, 256, 0, stream>>>(Ab, Wb, bq, Qw);
    cvt_f32_bf16<<<actg, 256, 0, stream>>>(key_, Ab, (int)(e / 8));
    cvt_f32_bf16<<<wg, 256, 0, stream>>>(Wk, Wb, (int)(w / 8));
    gemm_one<1, 128, __bf16><<<512, 256, 0, stream>>>(Ab, Wb, bk, Kw);
    cvt_f32_bf16<<<actg, 256, 0, stream>>>(value, Ab, (int)(e / 8));
    cvt_f32_bf16<<<wg, 256, 0, stream>>>(Wv, Wb, (int)(w / 8));
    gemm_one<2, 128, __bf16><<<512, 256, 0, stream>>>(Ab, Wb, bv, Vw);
    flash_attn<<<kB * kH * 16, 256, 0, stream>>>(Qw, Kw, Vw, Ab);
    cvt_f32_bf16<<<wg, 256, 0, stream>>>(Wo, Wb, (int)(w / 8));
    gemm_one<0, 64, float><<<1024, 256, 0, stream>>>(Ab, Wb, bo, out);
  }
}